// Round 2
// baseline (546.496 us; speedup 1.0000x reference)
//
#include <hip/hip_runtime.h>

// Problem constants (GCN_61065845014917)
#define B_   4
#define C_   1024
#define D_   768
#define H_   12
#define E_   32
#define K_   2
#define S_   24
#define V_   8
#define P_   512
#define NT_  256
#define EMB_ 768
#define BLK_ 64
#define NL_  97
#define DNT_ 1024     // D+NT
#define KHT_ 1792     // 2D+NT
#define KBIL_ 49152   // EMB*BLK
#define NPAD_ 128     // NL padded for MFMA

typedef __bf16 bf16x8 __attribute__((ext_vector_type(8)));
typedef float  f32x4  __attribute__((ext_vector_type(4)));

__device__ __forceinline__ float b2f(unsigned short u) {
    return (float)__builtin_bit_cast(__bf16, u);
}
__device__ __forceinline__ unsigned short f2b(float f) {
    return __builtin_bit_cast(unsigned short, (__bf16)f);   // RNE
}
// dtype-dispatched input load / output store (isf=1: f32 buffers, isf=0: bf16)
__device__ __forceinline__ float ld_in(const void* p, size_t i, int isf) {
    return isf ? ((const float*)p)[i] : b2f(((const unsigned short*)p)[i]);
}
__device__ __forceinline__ void st_out(void* p, size_t i, float v, int isf) {
    if (isf) ((float*)p)[i] = v;
    else     ((unsigned short*)p)[i] = f2b(v);
}

// ---------------------------------------------------------------------------
// K0: dtype probe. Inspect first 4096 even-index ushorts of sequence_output.
//  bf16 data: every ushort is a bf16 of ~N(0,1) -> |x| small, nonzero.
//  f32 data:  even-index ushorts are low mantissa halves -> random bits
//             (huge/NaN bf16 patterns common) or all-zero (bf16-upcast f32).
__global__ __launch_bounds__(256) void k_probe(const unsigned short* __restrict__ seq_u,
                                               int* __restrict__ flag)
{
    __shared__ int sh_huge[256];
    __shared__ int sh_zero[256];
    int tid = threadIdx.x;
    int huge = 0, zero = 0;
    for (int i = tid; i < 4096; i += 256) {
        unsigned short u = seq_u[2 * i];
        float f = b2f(u);
        if (!(fabsf(f) <= 1e10f)) huge = 1;   // catches NaN too
        if (u == 0) zero++;
    }
    sh_huge[tid] = huge; sh_zero[tid] = zero;
    __syncthreads();
    for (int s = 128; s > 0; s >>= 1) {
        if (tid < s) { sh_huge[tid] |= sh_huge[tid + s]; sh_zero[tid] += sh_zero[tid + s]; }
        __syncthreads();
    }
    if (tid == 0) flag[0] = (sh_huge[0] || sh_zero[0] > 3600) ? 1 : 0;
}

// ---------------------------------------------------------------------------
// K1: mention/sent/virtual gathers (exact copies) + entity logsumexp and
//     ent_hidden = [lse(mentions) | node_type] in f32.
// grid 256 = B*E(128) + B*S(96) + B*V(32), block 256
__global__ __launch_bounds__(256) void k_gather(
    const void* __restrict__ seq, const int* __restrict__ epos,
    const int* __restrict__ spos, const int* __restrict__ vpos,
    const void* __restrict__ ntype, float* __restrict__ enth,
    void* __restrict__ outv, long long moff, long long soff, long long voff,
    const int* __restrict__ dflag)
{
    int isf = *dflag;
    int blk = blockIdx.x, tid = threadIdx.x;
    if (blk < B_ * E_) {
        int b = blk / E_, e = blk % E_;
        int i0 = epos[(b * E_ + e) * K_ + 0] + 1;
        int i1 = epos[(b * E_ + e) * K_ + 1] + 1;
        size_t r0 = ((size_t)b * C_ + i0) * D_;
        size_t r1 = ((size_t)b * C_ + i1) * D_;
        size_t m0 = (size_t)moff + ((size_t)(b * E_ * K_) + 2 * e) * D_;
        size_t m1 = m0 + D_;
        float* eh = enth + (size_t)(b * E_ + e) * DNT_;
        for (int d = tid; d < D_; d += 256) {
            float a = ld_in(seq, r0 + d, isf);
            float c = ld_in(seq, r1 + d, isf);
            st_out(outv, m0 + d, a, isf);
            st_out(outv, m1 + d, c, isf);
            float mx = fmaxf(a, c);
            eh[d] = mx + logf(expf(a - mx) + expf(c - mx));
        }
        size_t nt0 = (size_t)(b * E_ + e) * NT_;
        for (int j = tid; j < NT_; j += 256) eh[D_ + j] = ld_in(ntype, nt0 + j, isf);
    } else if (blk < B_ * E_ + B_ * S_) {
        int t = blk - B_ * E_; int b = t / S_, s = t % S_;
        int i = spos[b * S_ + s] + 1;
        size_t r = ((size_t)b * C_ + i) * D_;
        size_t o = (size_t)soff + (size_t)(b * S_ + s) * D_;
        for (int d = tid; d < D_; d += 256) st_out(outv, o + d, ld_in(seq, r + d, isf), isf);
    } else {
        int t = blk - B_ * E_ - B_ * S_; int b = t / V_, v = t % V_;
        int i = vpos[b * V_ + v] + 1;
        size_t r = ((size_t)b * C_ + i) * D_;
        size_t o = (size_t)voff + (size_t)(b * V_ + v) * D_;
        for (int d = tid; d < D_; d += 256) st_out(outv, o + d, ld_in(seq, r + d, isf), isf);
    }
}

// ---------------------------------------------------------------------------
// K2: e_att[b,e,h,c] = mean_k attention[b,h,pos(b,e,k),c]  (f32)
// grid B*E*H = 1536
__global__ __launch_bounds__(256) void k_eatt(
    const void* __restrict__ att, const int* __restrict__ epos,
    float* __restrict__ e_att, const int* __restrict__ dflag)
{
    int isf = *dflag;
    int blk = blockIdx.x;
    int b = blk / (E_ * H_); int r = blk % (E_ * H_); int e = r / H_; int h = r % H_;
    int i0 = epos[(b * E_ + e) * K_ + 0] + 1;
    int i1 = epos[(b * E_ + e) * K_ + 1] + 1;
    size_t a0 = (((size_t)b * H_ + h) * C_ + i0) * C_;
    size_t a1 = (((size_t)b * H_ + h) * C_ + i1) * C_;
    float* o = e_att + (((size_t)(b * E_ + e)) * H_ + h) * C_;
    for (int c = threadIdx.x; c < C_; c += 256)
        o[c] = 0.5f * (ld_in(att, a0 + c, isf) + ld_in(att, a1 + c, isf));
}

// ---------------------------------------------------------------------------
// K3: ht_att[b,p,c] = mean_h e_att[he]*e_att[te], normalized over c; store bf16.
// grid B*P = 2048
__global__ __launch_bounds__(256) void k_htatt(
    const float* __restrict__ e_att, const int* __restrict__ hts,
    unsigned short* __restrict__ htb)
{
    int blk = blockIdx.x; int b = blk >> 9;
    int he = hts[blk * 2 + 0], te = hts[blk * 2 + 1];
    const float* ph = e_att + (size_t)(b * E_ + he) * H_ * C_;
    const float* pt = e_att + (size_t)(b * E_ + te) * H_ * C_;
    int tid = threadIdx.x;
    float v[4]; float ls = 0.f;
    for (int ci = 0; ci < 4; ci++) {
        int c = tid + (ci << 8);
        float acc = 0.f;
#pragma unroll
        for (int h = 0; h < H_; h++) acc += ph[h * C_ + c] * pt[h * C_ + c];
        acc *= (1.0f / (float)H_);
        v[ci] = acc; ls += acc;
    }
    for (int off = 32; off > 0; off >>= 1) ls += __shfl_down(ls, off, 64);
    __shared__ float red[4];
    if ((tid & 63) == 0) red[tid >> 6] = ls;
    __syncthreads();
    float inv = 1.0f / (red[0] + red[1] + red[2] + red[3] + 1e-5f);
    for (int ci = 0; ci < 4; ci++)
        htb[((size_t)blk << 10) + tid + (ci << 8)] = f2b(v[ci] * inv);
}

// ---------------------------------------------------------------------------
// Transposes: build Bt[n][k] bf16 layouts so MFMA B-fragments are contiguous.
__global__ __launch_bounds__(256) void k_t_seq(
    const void* __restrict__ seq, unsigned short* __restrict__ seqT,
    const int* __restrict__ dflag)
{
    int isf = *dflag;
    int blk = blockIdx.x;                 // b*192 + ct*12 + dt
    int b = blk / 192; int r = blk % 192; int ct = r / 12; int dt = r % 12;
    __shared__ unsigned short tile[64][65];
    for (int idx = threadIdx.x; idx < 4096; idx += 256) {
        int cc = idx >> 6, dd = idx & 63;
        tile[cc][dd] = f2b(ld_in(seq, ((size_t)b * C_ + ct * 64 + cc) * D_ + dt * 64 + dd, isf));
    }
    __syncthreads();
    for (int idx = threadIdx.x; idx < 4096; idx += 256) {
        int dd = idx >> 6, cc = idx & 63;
        seqT[((size_t)b * D_ + dt * 64 + dd) * C_ + ct * 64 + cc] = tile[cc][dd];
    }
}

__global__ __launch_bounds__(256) void k_t_w(
    const void* __restrict__ Wh, const void* __restrict__ Wt_,
    unsigned short* __restrict__ WtH, unsigned short* __restrict__ WtT,
    const int* __restrict__ dflag)
{
    int isf = *dflag;
    int blk = blockIdx.x;                 // mat*336 + kt*12 + nt
    int mat = blk / 336; int r = blk % 336; int kt = r / 12; int nt = r % 12;
    const void* in = mat ? Wt_ : Wh;
    unsigned short* out = mat ? WtT : WtH;
    __shared__ unsigned short tile[64][65];
    for (int idx = threadIdx.x; idx < 4096; idx += 256) {
        int kk = idx >> 6, nn = idx & 63;
        tile[kk][nn] = f2b(ld_in(in, ((size_t)kt * 64 + kk) * EMB_ + nt * 64 + nn, isf));
    }
    __syncthreads();
    for (int idx = threadIdx.x; idx < 4096; idx += 256) {
        int nn = idx >> 6, kk = idx & 63;
        out[((size_t)nt * 64 + nn) * KHT_ + kt * 64 + kk] = tile[kk][nn];
    }
}

// W_bil [49152][97] -> WtB [128][49152] (rows 97..127 zero)
__global__ __launch_bounds__(256) void k_t_bil(
    const void* __restrict__ Wb, unsigned short* __restrict__ WtB,
    const int* __restrict__ dflag)
{
    int isf = *dflag;
    int k0 = blockIdx.x << 8;             // 256 k per block, grid 192
    __shared__ unsigned short raw[256 * NL_];
    for (int idx = threadIdx.x; idx < 256 * NL_; idx += 256)
        raw[idx] = f2b(ld_in(Wb, (size_t)k0 * NL_ + idx, isf));
    __syncthreads();
    int kk = threadIdx.x;
    for (int n = 0; n < NPAD_; n++) {
        unsigned short v = (n < NL_) ? raw[kk * NL_ + n] : (unsigned short)0;
        WtB[(size_t)n * KBIL_ + k0 + kk] = v;
    }
}

// ---------------------------------------------------------------------------
// X rows, entity part: X[m][0..1023] = bf16(enth[b, hts[m][z]])
__global__ __launch_bounds__(256) void k_xbuild(
    const float* __restrict__ enth, const int* __restrict__ hts,
    unsigned short* __restrict__ Xh, unsigned short* __restrict__ Xt)
{
    int m = blockIdx.x; int b = m >> 9;
    int eh = hts[m * 2 + 0], et = hts[m * 2 + 1];
    const float* sh = enth + (size_t)(b * E_ + eh) * DNT_;
    const float* st = enth + (size_t)(b * E_ + et) * DNT_;
    for (int k = threadIdx.x; k < DNT_; k += 256) {
        Xh[(size_t)m * KHT_ + k] = f2b(sh[k]);
        Xt[(size_t)m * KHT_ + k] = f2b(st[k]);
    }
}

// ---------------------------------------------------------------------------
// Generic bf16 MFMA GEMM: C[m][n] = act(sum_k A[m][k] * Bt[n][k]).
// Block 256 thr = 4 waves (2x2), block tile 64x64, K step 32, 16x16x32 MFMA.
// mode 0: store bf16 into Xh/Xt at row (z*512+m), col 1024+n (rs epilogue)
// mode 1: outF[m*768+n] = tanhf(acc + bias[n])
__global__ __launch_bounds__(256) void k_gemm(
    const unsigned short* __restrict__ A, const unsigned short* __restrict__ Bt,
    int K, long long sAz, long long sBz, int mode,
    const void* __restrict__ bias, float* __restrict__ outF,
    unsigned short* __restrict__ oX1, unsigned short* __restrict__ oX2,
    const int* __restrict__ dflag)
{
    int n0 = blockIdx.x * 64, m0 = blockIdx.y * 64, z = blockIdx.z;
    const unsigned short* Ab = A + (size_t)z * sAz;
    const unsigned short* Bb = Bt + (size_t)z * sBz;
    __shared__ __align__(16) unsigned short a_lds[64][40];
    __shared__ __align__(16) unsigned short b_lds[64][40];
    int tid = threadIdx.x, lane = tid & 63, w = tid >> 6;
    int wm = (w >> 1) * 32, wn = (w & 1) * 32, q = lane >> 4, l15 = lane & 15;
    f32x4 acc00 = {0.f,0.f,0.f,0.f}, acc01 = acc00, acc10 = acc00, acc11 = acc00;
    int srow = tid >> 2, sch = (tid & 3) * 8;
    int nst = K >> 5;
    for (int ks = 0; ks < nst; ks++) {
        int k0 = ks << 5;
        __syncthreads();
        *(int4*)&a_lds[srow][sch] = *(const int4*)(Ab + (size_t)(m0 + srow) * K + k0 + sch);
        *(int4*)&b_lds[srow][sch] = *(const int4*)(Bb + (size_t)(n0 + srow) * K + k0 + sch);
        __syncthreads();
        bf16x8 a0 = *(const bf16x8*)&a_lds[wm + l15][q * 8];
        bf16x8 a1 = *(const bf16x8*)&a_lds[wm + 16 + l15][q * 8];
        bf16x8 b0 = *(const bf16x8*)&b_lds[wn + l15][q * 8];
        bf16x8 b1 = *(const bf16x8*)&b_lds[wn + 16 + l15][q * 8];
        acc00 = __builtin_amdgcn_mfma_f32_16x16x32_bf16(a0, b0, acc00, 0, 0, 0);
        acc01 = __builtin_amdgcn_mfma_f32_16x16x32_bf16(a0, b1, acc01, 0, 0, 0);
        acc10 = __builtin_amdgcn_mfma_f32_16x16x32_bf16(a1, b0, acc10, 0, 0, 0);
        acc11 = __builtin_amdgcn_mfma_f32_16x16x32_bf16(a1, b1, acc11, 0, 0, 0);
    }
    f32x4 accs[2][2] = {{acc00, acc01}, {acc10, acc11}};
    int isf = (mode == 1) ? *dflag : 0;
#pragma unroll
    for (int mt = 0; mt < 2; mt++)
#pragma unroll
        for (int nt = 0; nt < 2; nt++) {
            int gmb = m0 + wm + mt * 16 + q * 4;
            int gn  = n0 + wn + nt * 16 + l15;
            if (mode == 0) {
#pragma unroll
                for (int r = 0; r < 4; r++) {
                    unsigned short v = f2b(accs[mt][nt][r]);
                    size_t o = (size_t)(z * P_ + gmb + r) * KHT_ + DNT_ + gn;
                    oX1[o] = v; oX2[o] = v;
                }
            } else {
                float bv = ld_in(bias, gn, isf);
#pragma unroll
                for (int r = 0; r < 4; r++)
                    outF[(size_t)(gmb + r) * EMB_ + gn] = tanhf(accs[mt][nt][r] + bv);
            }
        }
}

// ---------------------------------------------------------------------------
// zero logitsF (2048*128 f32)
__global__ __launch_bounds__(256) void k_zero(float* __restrict__ p) {
    ((float4*)p)[blockIdx.x * 256 + threadIdx.x] = make_float4(0.f, 0.f, 0.f, 0.f);
}

// ---------------------------------------------------------------------------
// Grouped bilinear via MFMA, K split over groups (grid.y = g), atomic f32 acc.
// Block: 32 pairs (2 m-subtiles/wave) x 128 n (2 n-tiles/wave), 4 waves.
// A-frag built on the fly: X2[m][k=(i,j)] = hs[m, g*64+i] * ts[m, g*64+j].
__global__ __launch_bounds__(256) void k_bil(
    const float* __restrict__ hsF, const float* __restrict__ tsF,
    const unsigned short* __restrict__ WtB, float* __restrict__ logitsF)
{
    int m0 = blockIdx.x * 32;
    int g  = blockIdx.y;
    int tid = threadIdx.x, lane = tid & 63, w = tid >> 6;
    int q = lane >> 4, l15 = lane & 15;
    __shared__ __align__(16) float hsl[32][68];
    __shared__ __align__(16) float tsl[32][68];
    for (int idx = tid; idx < 2048; idx += 256) {
        int m = idx >> 6, j = idx & 63;
        hsl[m][j] = hsF[(size_t)(m0 + m) * EMB_ + g * 64 + j];
        tsl[m][j] = tsF[(size_t)(m0 + m) * EMB_ + g * 64 + j];
    }
    __syncthreads();

    const unsigned short* pB0 = WtB + (size_t)(w * 16 + l15) * KBIL_      + g * 4096 + q * 8;
    const unsigned short* pB1 = WtB + (size_t)(w * 16 + 64 + l15) * KBIL_ + g * 4096 + q * 8;
    bf16x8 bw0 = *(const bf16x8*)pB0;
    bf16x8 bw1 = *(const bf16x8*)pB1;
    f32x4 acc00 = {0.f,0.f,0.f,0.f}, acc01 = acc00, acc10 = acc00, acc11 = acc00;

    for (int kk = 0; kk < 128; kk++) {
        bf16x8 nb0 = bw0, nb1 = bw1;
        if (kk < 127) {
            nb0 = *(const bf16x8*)(pB0 + (size_t)(kk + 1) * 32);
            nb1 = *(const bf16x8*)(pB1 + (size_t)(kk + 1) * 32);
        }
        int i = kk >> 1, h = kk & 1;
        float ha0 = hsl[l15][i];
        float ha1 = hsl[16 + l15][i];
        const float4* t0p = (const float4*)&tsl[l15][h * 32 + q * 8];
        const float4* t1p = (const float4*)&tsl[16 + l15][h * 32 + q * 8];
        float4 t0a = t0p[0], t0b = t0p[1];
        float4 t1a = t1p[0], t1b = t1p[1];
        bf16x8 af0, af1;
        af0[0] = (__bf16)(ha0 * t0a.x); af0[1] = (__bf16)(ha0 * t0a.y);
        af0[2] = (__bf16)(ha0 * t0a.z); af0[3] = (__bf16)(ha0 * t0a.w);
        af0[4] = (__bf16)(ha0 * t0b.x); af0[5] = (__bf16)(ha0 * t0b.y);
        af0[6] = (__bf16)(ha0 * t0b.z); af0[7] = (__bf16)(ha0 * t0b.w);
        af1[0] = (__bf16)(ha1 * t1a.x); af1[1] = (__bf16)(ha1 * t1a.y);
        af1[2] = (__bf16)(ha1 * t1a.z); af1[3] = (__bf16)(ha1 * t1a.w);
        af1[4] = (__bf16)(ha1 * t1b.x); af1[5] = (__bf16)(ha1 * t1b.y);
        af1[6] = (__bf16)(ha1 * t1b.z); af1[7] = (__bf16)(ha1 * t1b.w);
        acc00 = __builtin_amdgcn_mfma_f32_16x16x32_bf16(af0, bw0, acc00, 0, 0, 0);
        acc01 = __builtin_amdgcn_mfma_f32_16x16x32_bf16(af0, bw1, acc01, 0, 0, 0);
        acc10 = __builtin_amdgcn_mfma_f32_16x16x32_bf16(af1, bw0, acc10, 0, 0, 0);
        acc11 = __builtin_amdgcn_mfma_f32_16x16x32_bf16(af1, bw1, acc11, 0, 0, 0);
        bw0 = nb0; bw1 = nb1;
    }
#pragma unroll
    for (int r = 0; r < 4; r++) {
        atomicAdd(&logitsF[(size_t)(m0 + q * 4 + r) * NPAD_ + w * 16 + l15],       acc00[r]);
        atomicAdd(&logitsF[(size_t)(m0 + q * 4 + r) * NPAD_ + w * 16 + 64 + l15],  acc01[r]);
        atomicAdd(&logitsF[(size_t)(m0 + 16 + q * 4 + r) * NPAD_ + w * 16 + l15],      acc10[r]);
        atomicAdd(&logitsF[(size_t)(m0 + 16 + q * 4 + r) * NPAD_ + w * 16 + 64 + l15], acc11[r]);
    }
}

// ---------------------------------------------------------------------------
// final: logits out with bias, n<97
__global__ __launch_bounds__(256) void k_fin(
    const float* __restrict__ logitsF, const void* __restrict__ b_bil,
    void* __restrict__ outv, const int* __restrict__ dflag)
{
    int isf = *dflag;
    int idx = blockIdx.x * 256 + threadIdx.x;
    if (idx >= B_ * P_ * NL_) return;
    int m = idx / NL_, n = idx % NL_;
    st_out(outv, idx, logitsF[(size_t)m * NPAD_ + n] + ld_in(b_bil, n, isf), isf);
}

// ---------------------------------------------------------------------------
extern "C" void kernel_launch(void* const* d_in, const int* in_sizes, int n_in,
                              void* d_out, int out_size, void* d_ws, size_t ws_size,
                              hipStream_t stream)
{
    const void* seq    = d_in[0];
    const void* att    = d_in[1];
    const int*  epos   = (const int*)d_in[2];
    const int*  spos   = (const int*)d_in[3];
    const int*  vpos   = (const int*)d_in[4];
    const int*  hts    = (const int*)d_in[5];
    const void* ntype  = d_in[6];
    const void* W_head = d_in[7];
    const void* b_head = d_in[8];
    const void* W_tail = d_in[9];
    const void* b_tail = d_in[10];
    const void* W_bil  = d_in[11];
    const void* b_bil  = d_in[12];

    // output element offsets (dtype-agnostic)
    long long logits_off  = 0;
    long long mention_off = (long long)B_ * P_ * NL_;
    long long sent_off    = mention_off + (long long)B_ * E_ * K_ * D_;
    long long virt_off    = sent_off + (long long)B_ * S_ * D_;

    // workspace carve (~64 MB)
    char* p = (char*)d_ws;
    auto alloc = [&](size_t bytes) { void* r = (void*)p; p += (bytes + 255) & ~(size_t)255; return r; };
    int*            dflag   = (int*)alloc(256);
    float*          e_att   = (float*)alloc((size_t)B_ * E_ * H_ * C_ * 4);
    unsigned short* htb     = (unsigned short*)alloc((size_t)B_ * P_ * C_ * 2);
    unsigned short* seqT    = (unsigned short*)alloc((size_t)B_ * D_ * C_ * 2);
    unsigned short* WtH     = (unsigned short*)alloc((size_t)EMB_ * KHT_ * 2);
    unsigned short* WtT     = (unsigned short*)alloc((size_t)EMB_ * KHT_ * 2);
    unsigned short* WtB     = (unsigned short*)alloc((size_t)NPAD_ * KBIL_ * 2);
    unsigned short* Xh      = (unsigned short*)alloc((size_t)B_ * P_ * KHT_ * 2);
    unsigned short* Xt      = (unsigned short*)alloc((size_t)B_ * P_ * KHT_ * 2);
    float*          hsF     = (float*)alloc((size_t)B_ * P_ * EMB_ * 4);
    float*          tsF     = (float*)alloc((size_t)B_ * P_ * EMB_ * 4);
    float*          logitsF = (float*)alloc((size_t)B_ * P_ * NPAD_ * 4);
    float*          enth    = (float*)alloc((size_t)B_ * E_ * DNT_ * 4);

    dim3 blk(256);
    k_probe<<<1, blk, 0, stream>>>((const unsigned short*)seq, dflag);
    k_gather<<<256, blk, 0, stream>>>(seq, epos, spos, vpos, ntype, enth,
                                      d_out, mention_off, sent_off, virt_off, dflag);
    k_eatt<<<B_ * E_ * H_, blk, 0, stream>>>(att, epos, e_att, dflag);
    k_htatt<<<B_ * P_, blk, 0, stream>>>(e_att, hts, htb);
    k_t_seq<<<768, blk, 0, stream>>>(seq, seqT, dflag);
    k_t_w<<<672, blk, 0, stream>>>(W_head, W_tail, WtH, WtT, dflag);
    k_t_bil<<<192, blk, 0, stream>>>(W_bil, WtB, dflag);
    k_xbuild<<<B_ * P_, blk, 0, stream>>>(enth, hts, Xh, Xt);
    // rs GEMM: per batch [512 x 1024] @ [1024 x 768] -> X cols 1024..1791 (bf16)
    k_gemm<<<dim3(EMB_ / 64, P_ / 64, B_), blk, 0, stream>>>(
        htb, seqT, C_, (long long)P_ * C_, (long long)D_ * C_, 0,
        nullptr, nullptr, Xh, Xt, dflag);
    // head / tail extractors: [2048 x 1792] @ [1792 x 768], tanh epilogue -> f32
    k_gemm<<<dim3(EMB_ / 64, (B_ * P_) / 64, 1), blk, 0, stream>>>(
        Xh, WtH, KHT_, 0, 0, 1, b_head, hsF, nullptr, nullptr, dflag);
    k_gemm<<<dim3(EMB_ / 64, (B_ * P_) / 64, 1), blk, 0, stream>>>(
        Xt, WtT, KHT_, 0, 0, 1, b_tail, tsF, nullptr, nullptr, dflag);
    k_zero<<<(B_ * P_ * NPAD_) / 1024, blk, 0, stream>>>(logitsF);
    k_bil<<<dim3((B_ * P_) / 32, 12, 1), blk, 0, stream>>>(hsF, tsF, WtB, logitsF);
    k_fin<<<(B_ * P_ * NL_ + 255) / 256, blk, 0, stream>>>(logitsF, b_bil, d_out, dflag);
}

// Round 3
// 473.095 us; speedup vs baseline: 1.1552x; 1.1552x over previous
//
#include <hip/hip_runtime.h>

// Problem constants (GCN_61065845014917)
#define B_   4
#define C_   1024
#define D_   768
#define H_   12
#define E_   32
#define K_   2
#define S_   24
#define V_   8
#define P_   512
#define NT_  256
#define EMB_ 768
#define BLK_ 64
#define NL_  97
#define DNT_ 1024     // D+NT
#define KHT_ 1792     // 2D+NT
#define KBIL_ 49152   // EMB*BLK
#define NPAD_ 128     // NL padded for MFMA

typedef __bf16 bf16x8 __attribute__((ext_vector_type(8)));
typedef float  f32x4  __attribute__((ext_vector_type(4)));

__device__ __forceinline__ float b2f(unsigned short u) {
    return (float)__builtin_bit_cast(__bf16, u);
}
__device__ __forceinline__ unsigned short f2b(float f) {
    return __builtin_bit_cast(unsigned short, (__bf16)f);   // RNE
}
// dtype-dispatched input load / output store (isf=1: f32 buffers, isf=0: bf16)
__device__ __forceinline__ float ld_in(const void* p, size_t i, int isf) {
    return isf ? ((const float*)p)[i] : b2f(((const unsigned short*)p)[i]);
}
__device__ __forceinline__ void st_out(void* p, size_t i, float v, int isf) {
    if (isf) ((float*)p)[i] = v;
    else     ((unsigned short*)p)[i] = f2b(v);
}

// ---------------------------------------------------------------------------
// K0: dtype probe (see R1 notes). flag=1 -> inputs are f32, 0 -> bf16.
__global__ __launch_bounds__(256) void k_probe(const unsigned short* __restrict__ seq_u,
                                               int* __restrict__ flag)
{
    __shared__ int sh_huge[256];
    __shared__ int sh_zero[256];
    int tid = threadIdx.x;
    int huge = 0, zero = 0;
    for (int i = tid; i < 4096; i += 256) {
        unsigned short u = seq_u[2 * i];
        float f = b2f(u);
        if (!(fabsf(f) <= 1e10f)) huge = 1;   // catches NaN too
        if (u == 0) zero++;
    }
    sh_huge[tid] = huge; sh_zero[tid] = zero;
    __syncthreads();
    for (int s = 128; s > 0; s >>= 1) {
        if (tid < s) { sh_huge[tid] |= sh_huge[tid + s]; sh_zero[tid] += sh_zero[tid + s]; }
        __syncthreads();
    }
    if (tid == 0) flag[0] = (sh_huge[0] || sh_zero[0] > 3600) ? 1 : 0;
}

// ---------------------------------------------------------------------------
// K1 fused prep: [0,256) gather, [256,1792) eatt, [1792,2560) t_seq,
//                [2560,3232) t_w, [3232,4000) t_bil(64k/blk)
#define PREP_GATHER 256
#define PREP_EATT   (PREP_GATHER + B_*E_*H_)     // +1536 -> 1792
#define PREP_TSEQ   (PREP_EATT + 768)            // -> 2560
#define PREP_TW     (PREP_TSEQ + 672)            // -> 3232
#define PREP_TBIL   (PREP_TW + 768)              // -> 4000

__global__ __launch_bounds__(256) void k_prep(
    const void* __restrict__ seq, const void* __restrict__ att,
    const int* __restrict__ epos, const int* __restrict__ spos,
    const int* __restrict__ vpos, const void* __restrict__ ntype,
    const void* __restrict__ Wh, const void* __restrict__ Wt_,
    const void* __restrict__ Wb,
    float* __restrict__ enth, float* __restrict__ e_att,
    unsigned short* __restrict__ seqT,
    unsigned short* __restrict__ WtH, unsigned short* __restrict__ WtT,
    unsigned short* __restrict__ WtB,
    void* __restrict__ outv, long long moff, long long soff, long long voff,
    const int* __restrict__ dflag)
{
    __shared__ __align__(16) unsigned char smem[12544];
    int blk = blockIdx.x, tid = threadIdx.x;
    int isf = *dflag;
    if (blk < PREP_GATHER) {
        if (blk < B_ * E_) {
            int b = blk / E_, e = blk % E_;
            int i0 = epos[(b * E_ + e) * K_ + 0] + 1;
            int i1 = epos[(b * E_ + e) * K_ + 1] + 1;
            size_t r0 = ((size_t)b * C_ + i0) * D_;
            size_t r1 = ((size_t)b * C_ + i1) * D_;
            size_t m0 = (size_t)moff + ((size_t)(b * E_ * K_) + 2 * e) * D_;
            size_t m1 = m0 + D_;
            float* eh = enth + (size_t)(b * E_ + e) * DNT_;
            for (int d = tid; d < D_; d += 256) {
                float a = ld_in(seq, r0 + d, isf);
                float c = ld_in(seq, r1 + d, isf);
                st_out(outv, m0 + d, a, isf);
                st_out(outv, m1 + d, c, isf);
                float mx = fmaxf(a, c);
                eh[d] = mx + logf(expf(a - mx) + expf(c - mx));
            }
            size_t nt0 = (size_t)(b * E_ + e) * NT_;
            for (int j = tid; j < NT_; j += 256) eh[D_ + j] = ld_in(ntype, nt0 + j, isf);
        } else if (blk < B_ * E_ + B_ * S_) {
            int t = blk - B_ * E_; int b = t / S_, s = t % S_;
            int i = spos[b * S_ + s] + 1;
            size_t r = ((size_t)b * C_ + i) * D_;
            size_t o = (size_t)soff + (size_t)(b * S_ + s) * D_;
            for (int d = tid; d < D_; d += 256) st_out(outv, o + d, ld_in(seq, r + d, isf), isf);
        } else {
            int t = blk - B_ * E_ - B_ * S_; int b = t / V_, v = t % V_;
            int i = vpos[b * V_ + v] + 1;
            size_t r = ((size_t)b * C_ + i) * D_;
            size_t o = (size_t)voff + (size_t)(b * V_ + v) * D_;
            for (int d = tid; d < D_; d += 256) st_out(outv, o + d, ld_in(seq, r + d, isf), isf);
        }
    } else if (blk < PREP_EATT) {
        int t = blk - PREP_GATHER;
        int b = t / (E_ * H_); int r = t % (E_ * H_); int e = r / H_; int h = r % H_;
        int i0 = epos[(b * E_ + e) * K_ + 0] + 1;
        int i1 = epos[(b * E_ + e) * K_ + 1] + 1;
        size_t a0 = (((size_t)b * H_ + h) * C_ + i0) * C_;
        size_t a1 = (((size_t)b * H_ + h) * C_ + i1) * C_;
        float* o = e_att + (((size_t)(b * E_ + e)) * H_ + h) * C_;
        for (int c = tid; c < C_; c += 256)
            o[c] = 0.5f * (ld_in(att, a0 + c, isf) + ld_in(att, a1 + c, isf));
    } else if (blk < PREP_TSEQ) {
        int t = blk - PREP_EATT;                 // b*192 + ct*12 + dt
        int b = t / 192; int r = t % 192; int ct = r / 12; int dt = r % 12;
        typedef unsigned short row65[65];
        row65* tile = (row65*)smem;
        for (int idx = tid; idx < 4096; idx += 256) {
            int cc = idx >> 6, dd = idx & 63;
            tile[cc][dd] = f2b(ld_in(seq, ((size_t)b * C_ + ct * 64 + cc) * D_ + dt * 64 + dd, isf));
        }
        __syncthreads();
        for (int idx = tid; idx < 4096; idx += 256) {
            int dd = idx >> 6, cc = idx & 63;
            seqT[((size_t)b * D_ + dt * 64 + dd) * C_ + ct * 64 + cc] = tile[cc][dd];
        }
    } else if (blk < PREP_TW) {
        int t = blk - PREP_TSEQ;                 // mat*336 + kt*12 + nt
        int mat = t / 336; int r = t % 336; int kt = r / 12; int nt = r % 12;
        const void* in = mat ? Wt_ : Wh;
        unsigned short* out = mat ? WtT : WtH;
        typedef unsigned short row65[65];
        row65* tile = (row65*)smem;
        for (int idx = tid; idx < 4096; idx += 256) {
            int kk = idx >> 6, nn = idx & 63;
            tile[kk][nn] = f2b(ld_in(in, ((size_t)kt * 64 + kk) * EMB_ + nt * 64 + nn, isf));
        }
        __syncthreads();
        for (int idx = tid; idx < 4096; idx += 256) {
            int nn = idx >> 6, kk = idx & 63;
            out[((size_t)nt * 64 + nn) * KHT_ + kt * 64 + kk] = tile[kk][nn];
        }
    } else {
        int t = blk - PREP_TW;                   // 64 k-cols per block
        int k0 = t << 6;
        unsigned short* raw = (unsigned short*)smem;   // [64*97]
        for (int idx = tid; idx < 64 * NL_; idx += 256)
            raw[idx] = f2b(ld_in(Wb, (size_t)k0 * NL_ + idx, isf));
        __syncthreads();
        int kk = tid & 63, nq = tid >> 6;              // 4 quarters x 32 n
        for (int i = 0; i < 32; i++) {
            int n = nq * 32 + i;
            unsigned short v = (n < NL_) ? raw[kk * NL_ + n] : (unsigned short)0;
            WtB[(size_t)n * KBIL_ + k0 + kk] = v;
        }
    }
}

// ---------------------------------------------------------------------------
// K2 fused mid: [0,2048) htatt, [2048,4096) xbuild
__global__ __launch_bounds__(256) void k_mid(
    const float* __restrict__ e_att, const float* __restrict__ enth,
    const int* __restrict__ hts,
    unsigned short* __restrict__ htb,
    unsigned short* __restrict__ Xh, unsigned short* __restrict__ Xt)
{
    __shared__ float red[4];
    int blk = blockIdx.x, tid = threadIdx.x;
    if (blk < B_ * P_) {
        int b = blk >> 9;
        int he = hts[blk * 2 + 0], te = hts[blk * 2 + 1];
        const float* ph = e_att + (size_t)(b * E_ + he) * H_ * C_;
        const float* pt = e_att + (size_t)(b * E_ + te) * H_ * C_;
        float v[4]; float ls = 0.f;
        for (int ci = 0; ci < 4; ci++) {
            int c = tid + (ci << 8);
            float acc = 0.f;
#pragma unroll
            for (int h = 0; h < H_; h++) acc += ph[h * C_ + c] * pt[h * C_ + c];
            acc *= (1.0f / (float)H_);
            v[ci] = acc; ls += acc;
        }
        for (int off = 32; off > 0; off >>= 1) ls += __shfl_down(ls, off, 64);
        if ((tid & 63) == 0) red[tid >> 6] = ls;
        __syncthreads();
        float inv = 1.0f / (red[0] + red[1] + red[2] + red[3] + 1e-5f);
        for (int ci = 0; ci < 4; ci++)
            htb[((size_t)blk << 10) + tid + (ci << 8)] = f2b(v[ci] * inv);
    } else {
        int m = blk - B_ * P_; int b = m >> 9;
        int eh = hts[m * 2 + 0], et = hts[m * 2 + 1];
        const float* sh = enth + (size_t)(b * E_ + eh) * DNT_;
        const float* st = enth + (size_t)(b * E_ + et) * DNT_;
        for (int k = tid; k < DNT_; k += 256) {
            Xh[(size_t)m * KHT_ + k] = f2b(sh[k]);
            Xt[(size_t)m * KHT_ + k] = f2b(st[k]);
        }
    }
}

// ---------------------------------------------------------------------------
// zero the contiguous hsF|tsF|logitsF region (3407872 floats)
__global__ __launch_bounds__(256) void k_zero(float* __restrict__ p) {
    ((float4*)p)[(size_t)blockIdx.x * 256 + threadIdx.x] = make_float4(0.f, 0.f, 0.f, 0.f);
}

// ---------------------------------------------------------------------------
// bf16 MFMA GEMM, 64x64 tile, 4 waves 2x2, K-step 32, register prefetch.
// zmode 0 (rs): z = batch; epilogue writes bf16 into Xh/Xt cols DNT_+n.
// zmode 1 (ht): z = mat*2 + khalf; atomicAdd f32 partials into hsF/tsF.
__global__ __launch_bounds__(256) void k_gemm(
    const unsigned short* __restrict__ A0, const unsigned short* __restrict__ A1,
    const unsigned short* __restrict__ B0, const unsigned short* __restrict__ B1,
    long long lda, long long ldb, long long sAz, long long sBz,
    int nsteps, int zmode,
    float* __restrict__ outF0, float* __restrict__ outF1,
    unsigned short* __restrict__ oX1, unsigned short* __restrict__ oX2)
{
    int n0 = blockIdx.x * 64, m0 = blockIdx.y * 64, z = blockIdx.z;
    const unsigned short* Ab; const unsigned short* Bb;
    float* outF = nullptr; int kc0 = 0;
    if (zmode == 0) {
        Ab = A0 + (size_t)z * sAz; Bb = B0 + (size_t)z * sBz;
    } else {
        int mat = z >> 1, kh = z & 1;
        Ab = mat ? A1 : A0; Bb = mat ? B1 : B0;
        outF = mat ? outF1 : outF0;
        kc0 = kh * (nsteps * 32);
    }
    __shared__ __align__(16) unsigned short a_lds[64][40];
    __shared__ __align__(16) unsigned short b_lds[64][40];
    int tid = threadIdx.x, lane = tid & 63, w = tid >> 6;
    int wm = (w >> 1) * 32, wn = (w & 1) * 32, q = lane >> 4, l15 = lane & 15;
    f32x4 acc00 = {0.f,0.f,0.f,0.f}, acc01 = acc00, acc10 = acc00, acc11 = acc00;
    int srow = tid >> 2, sch = (tid & 3) * 8;
    const unsigned short* pa = Ab + (size_t)(m0 + srow) * lda + kc0 + sch;
    const unsigned short* pb = Bb + (size_t)(n0 + srow) * ldb + kc0 + sch;
    int4 ra = *(const int4*)pa;
    int4 rb = *(const int4*)pb;
    for (int ks = 0; ks < nsteps; ks++) {
        __syncthreads();
        *(int4*)&a_lds[srow][sch] = ra;
        *(int4*)&b_lds[srow][sch] = rb;
        __syncthreads();
        if (ks + 1 < nsteps) {
            ra = *(const int4*)(pa + (size_t)(ks + 1) * 32);
            rb = *(const int4*)(pb + (size_t)(ks + 1) * 32);
        }
        bf16x8 a0 = *(const bf16x8*)&a_lds[wm + l15][q * 8];
        bf16x8 a1 = *(const bf16x8*)&a_lds[wm + 16 + l15][q * 8];
        bf16x8 b0 = *(const bf16x8*)&b_lds[wn + l15][q * 8];
        bf16x8 b1 = *(const bf16x8*)&b_lds[wn + 16 + l15][q * 8];
        acc00 = __builtin_amdgcn_mfma_f32_16x16x32_bf16(a0, b0, acc00, 0, 0, 0);
        acc01 = __builtin_amdgcn_mfma_f32_16x16x32_bf16(a0, b1, acc01, 0, 0, 0);
        acc10 = __builtin_amdgcn_mfma_f32_16x16x32_bf16(a1, b0, acc10, 0, 0, 0);
        acc11 = __builtin_amdgcn_mfma_f32_16x16x32_bf16(a1, b1, acc11, 0, 0, 0);
    }
    f32x4 accs[2][2] = {{acc00, acc01}, {acc10, acc11}};
#pragma unroll
    for (int mt = 0; mt < 2; mt++)
#pragma unroll
        for (int nt = 0; nt < 2; nt++) {
            int gmb = m0 + wm + mt * 16 + q * 4;
            int gn  = n0 + wn + nt * 16 + l15;
            if (zmode == 0) {
#pragma unroll
                for (int r = 0; r < 4; r++) {
                    unsigned short v = f2b(accs[mt][nt][r]);
                    size_t o = (size_t)(z * P_ + gmb + r) * KHT_ + DNT_ + gn;
                    oX1[o] = v; oX2[o] = v;
                }
            } else {
#pragma unroll
                for (int r = 0; r < 4; r++)
                    atomicAdd(&outF[(size_t)(gmb + r) * EMB_ + gn], accs[mt][nt][r]);
            }
        }
}

// ---------------------------------------------------------------------------
// Grouped bilinear via MFMA, K split over groups (grid.y = g), atomic f32 acc.
// Stage applies tanh(raw + bias). Depth-2 B-fragment prefetch.
__global__ __launch_bounds__(256) void k_bil(
    const float* __restrict__ hsF, const float* __restrict__ tsF,
    const void* __restrict__ b_head, const void* __restrict__ b_tail,
    const unsigned short* __restrict__ WtB, float* __restrict__ logitsF,
    const int* __restrict__ dflag)
{
    int m0 = blockIdx.x * 32;
    int g  = blockIdx.y;
    int isf = *dflag;
    int tid = threadIdx.x, lane = tid & 63, w = tid >> 6;
    int q = lane >> 4, l15 = lane & 15;
    __shared__ __align__(16) float hsl[32][68];
    __shared__ __align__(16) float tsl[32][68];
    for (int idx = tid; idx < 2048; idx += 256) {
        int m = idx >> 6, j = idx & 63;
        int col = g * 64 + j;
        float bh = ld_in(b_head, col, isf);
        float bt = ld_in(b_tail, col, isf);
        hsl[m][j] = tanhf(hsF[(size_t)(m0 + m) * EMB_ + col] + bh);
        tsl[m][j] = tanhf(tsF[(size_t)(m0 + m) * EMB_ + col] + bt);
    }
    __syncthreads();

    const unsigned short* pB0 = WtB + (size_t)(w * 16 + l15) * KBIL_ + g * 4096 + q * 8;
    const unsigned short* pB1 = pB0 + (size_t)64 * KBIL_;
    bf16x8 rb0[2], rb1[2];
    rb0[0] = *(const bf16x8*)(pB0);      rb1[0] = *(const bf16x8*)(pB1);
    rb0[1] = *(const bf16x8*)(pB0 + 32); rb1[1] = *(const bf16x8*)(pB1 + 32);
    f32x4 acc00 = {0.f,0.f,0.f,0.f}, acc01 = acc00, acc10 = acc00, acc11 = acc00;

#pragma unroll 2
    for (int kk = 0; kk < 128; kk++) {
        int sl = kk & 1;
        bf16x8 bw0 = rb0[sl], bw1 = rb1[sl];
        if (kk + 2 < 128) {
            rb0[sl] = *(const bf16x8*)(pB0 + (size_t)(kk + 2) * 32);
            rb1[sl] = *(const bf16x8*)(pB1 + (size_t)(kk + 2) * 32);
        }
        int i = kk >> 1, h = kk & 1;
        float ha0 = hsl[l15][i];
        float ha1 = hsl[16 + l15][i];
        const float4* t0p = (const float4*)&tsl[l15][h * 32 + q * 8];
        const float4* t1p = (const float4*)&tsl[16 + l15][h * 32 + q * 8];
        float4 t0a = t0p[0], t0b = t0p[1];
        float4 t1a = t1p[0], t1b = t1p[1];
        bf16x8 af0, af1;
        af0[0] = (__bf16)(ha0 * t0a.x); af0[1] = (__bf16)(ha0 * t0a.y);
        af0[2] = (__bf16)(ha0 * t0a.z); af0[3] = (__bf16)(ha0 * t0a.w);
        af0[4] = (__bf16)(ha0 * t0b.x); af0[5] = (__bf16)(ha0 * t0b.y);
        af0[6] = (__bf16)(ha0 * t0b.z); af0[7] = (__bf16)(ha0 * t0b.w);
        af1[0] = (__bf16)(ha1 * t1a.x); af1[1] = (__bf16)(ha1 * t1a.y);
        af1[2] = (__bf16)(ha1 * t1a.z); af1[3] = (__bf16)(ha1 * t1a.w);
        af1[4] = (__bf16)(ha1 * t1b.x); af1[5] = (__bf16)(ha1 * t1b.y);
        af1[6] = (__bf16)(ha1 * t1b.z); af1[7] = (__bf16)(ha1 * t1b.w);
        acc00 = __builtin_amdgcn_mfma_f32_16x16x32_bf16(af0, bw0, acc00, 0, 0, 0);
        acc01 = __builtin_amdgcn_mfma_f32_16x16x32_bf16(af0, bw1, acc01, 0, 0, 0);
        acc10 = __builtin_amdgcn_mfma_f32_16x16x32_bf16(af1, bw0, acc10, 0, 0, 0);
        acc11 = __builtin_amdgcn_mfma_f32_16x16x32_bf16(af1, bw1, acc11, 0, 0, 0);
    }
#pragma unroll
    for (int r = 0; r < 4; r++) {
        atomicAdd(&logitsF[(size_t)(m0 + q * 4 + r) * NPAD_ + w * 16 + l15],           acc00[r]);
        atomicAdd(&logitsF[(size_t)(m0 + q * 4 + r) * NPAD_ + w * 16 + 64 + l15],      acc01[r]);
        atomicAdd(&logitsF[(size_t)(m0 + 16 + q * 4 + r) * NPAD_ + w * 16 + l15],      acc10[r]);
        atomicAdd(&logitsF[(size_t)(m0 + 16 + q * 4 + r) * NPAD_ + w * 16 + 64 + l15], acc11[r]);
    }
}

// ---------------------------------------------------------------------------
// final: logits out with bias, n<97
__global__ __launch_bounds__(256) void k_fin(
    const float* __restrict__ logitsF, const void* __restrict__ b_bil,
    void* __restrict__ outv, const int* __restrict__ dflag)
{
    int isf = *dflag;
    int idx = blockIdx.x * 256 + threadIdx.x;
    if (idx >= B_ * P_ * NL_) return;
    int m = idx / NL_, n = idx % NL_;
    st_out(outv, idx, logitsF[(size_t)m * NPAD_ + n] + ld_in(b_bil, n, isf), isf);
}

// ---------------------------------------------------------------------------
extern "C" void kernel_launch(void* const* d_in, const int* in_sizes, int n_in,
                              void* d_out, int out_size, void* d_ws, size_t ws_size,
                              hipStream_t stream)
{
    const void* seq    = d_in[0];
    const void* att    = d_in[1];
    const int*  epos   = (const int*)d_in[2];
    const int*  spos   = (const int*)d_in[3];
    const int*  vpos   = (const int*)d_in[4];
    const int*  hts    = (const int*)d_in[5];
    const void* ntype  = d_in[6];
    const void* W_head = d_in[7];
    const void* b_head = d_in[8];
    const void* W_tail = d_in[9];
    const void* b_tail = d_in[10];
    const void* W_bil  = d_in[11];
    const void* b_bil  = d_in[12];

    // output element offsets (dtype-agnostic)
    long long mention_off = (long long)B_ * P_ * NL_;
    long long sent_off    = mention_off + (long long)B_ * E_ * K_ * D_;
    long long virt_off    = sent_off + (long long)B_ * S_ * D_;

    // workspace carve (~64 MB). hsF|tsF|logitsF MUST stay contiguous (k_zero).
    char* p = (char*)d_ws;
    auto alloc = [&](size_t bytes) { void* r = (void*)p; p += (bytes + 255) & ~(size_t)255; return r; };
    int*            dflag   = (int*)alloc(256);
    float*          e_att   = (float*)alloc((size_t)B_ * E_ * H_ * C_ * 4);
    unsigned short* htb     = (unsigned short*)alloc((size_t)B_ * P_ * C_ * 2);
    unsigned short* seqT    = (unsigned short*)alloc((size_t)B_ * D_ * C_ * 2);
    unsigned short* WtH     = (unsigned short*)alloc((size_t)EMB_ * KHT_ * 2);
    unsigned short* WtT     = (unsigned short*)alloc((size_t)EMB_ * KHT_ * 2);
    unsigned short* WtB     = (unsigned short*)alloc((size_t)NPAD_ * KBIL_ * 2);
    unsigned short* Xh      = (unsigned short*)alloc((size_t)B_ * P_ * KHT_ * 2);
    unsigned short* Xt      = (unsigned short*)alloc((size_t)B_ * P_ * KHT_ * 2);
    float*          hsF     = (float*)alloc((size_t)B_ * P_ * EMB_ * 4);     // contiguous
    float*          tsF     = (float*)alloc((size_t)B_ * P_ * EMB_ * 4);     // contiguous
    float*          logitsF = (float*)alloc((size_t)B_ * P_ * NPAD_ * 4);    // contiguous
    float*          enth    = (float*)alloc((size_t)B_ * E_ * DNT_ * 4);

    dim3 blk(256);
    k_probe<<<1, blk, 0, stream>>>((const unsigned short*)seq, dflag);
    k_prep<<<PREP_TBIL, blk, 0, stream>>>(
        seq, att, epos, spos, vpos, ntype, W_head, W_tail, W_bil,
        enth, e_att, seqT, WtH, WtT, WtB,
        d_out, mention_off, sent_off, virt_off, dflag);
    k_mid<<<2 * B_ * P_, blk, 0, stream>>>(e_att, enth, hts, htb, Xh, Xt);
    // zero hsF..logitsF: (2048*768*2 + 2048*128) floats / 4 / 256 = 3328 blocks
    k_zero<<<3328, blk, 0, stream>>>(hsF);
    // rs GEMM: per batch [512 x 1024] @ [1024 x 768] -> X cols 1024..1791 (bf16)
    k_gemm<<<dim3(EMB_ / 64, P_ / 64, B_), blk, 0, stream>>>(
        htb, nullptr, seqT, nullptr, C_, C_,
        (long long)P_ * C_, (long long)D_ * C_, C_ / 32, 0,
        nullptr, nullptr, Xh, Xt);
    // fused head+tail, K-split 2: [2048 x 1792] @ [1792 x 768] -> atomic f32
    k_gemm<<<dim3(EMB_ / 64, (B_ * P_) / 64, 4), blk, 0, stream>>>(
        Xh, Xt, WtH, WtT, KHT_, KHT_, 0, 0, KHT_ / 64, 1,
        hsF, tsF, nullptr, nullptr);
    k_bil<<<dim3((B_ * P_) / 32, 12, 1), blk, 0, stream>>>(
        hsF, tsF, b_head, b_tail, WtB, logitsF, dflag);
    k_fin<<<(B_ * P_ * NL_ + 255) / 256, blk, 0, stream>>>(logitsF, b_bil, d_out, dflag);
}

// Round 4
// 453.890 us; speedup vs baseline: 1.2040x; 1.0423x over previous
//
#include <hip/hip_runtime.h>

// Problem constants (GCN_61065845014917)
#define B_   4
#define C_   1024
#define D_   768
#define H_   12
#define E_   32
#define K_   2
#define S_   24
#define V_   8
#define P_   512
#define NT_  256
#define EMB_ 768
#define BLK_ 64
#define NL_  97
#define DNT_ 1024     // D+NT
#define KHT_ 1792     // 2D+NT
#define KBIL_ 49152   // EMB*BLK
#define NPAD_ 128     // NL padded for MFMA

typedef __bf16 bf16x8 __attribute__((ext_vector_type(8)));
typedef float  f32x4  __attribute__((ext_vector_type(4)));

__device__ __forceinline__ float b2f(unsigned short u) {
    return (float)__builtin_bit_cast(__bf16, u);
}
__device__ __forceinline__ unsigned short f2b(float f) {
    return __builtin_bit_cast(unsigned short, (__bf16)f);   // RNE
}
// dtype-dispatched input load / output store (isf=1: f32 buffers, isf=0: bf16)
__device__ __forceinline__ float ld_in(const void* p, size_t i, int isf) {
    return isf ? ((const float*)p)[i] : b2f(((const unsigned short*)p)[i]);
}
__device__ __forceinline__ void st_out(void* p, size_t i, float v, int isf) {
    if (isf) ((float*)p)[i] = v;
    else     ((unsigned short*)p)[i] = f2b(v);
}

// ---------------------------------------------------------------------------
// K0: dtype probe (see R1 notes). flag=1 -> inputs are f32, 0 -> bf16.
__global__ __launch_bounds__(256) void k_probe(const unsigned short* __restrict__ seq_u,
                                               int* __restrict__ flag)
{
    __shared__ int sh_huge[256];
    __shared__ int sh_zero[256];
    int tid = threadIdx.x;
    int huge = 0, zero = 0;
    for (int i = tid; i < 4096; i += 256) {
        unsigned short u = seq_u[2 * i];
        float f = b2f(u);
        if (!(fabsf(f) <= 1e10f)) huge = 1;   // catches NaN too
        if (u == 0) zero++;
    }
    sh_huge[tid] = huge; sh_zero[tid] = zero;
    __syncthreads();
    for (int s = 128; s > 0; s >>= 1) {
        if (tid < s) { sh_huge[tid] |= sh_huge[tid + s]; sh_zero[tid] += sh_zero[tid + s]; }
        __syncthreads();
    }
    if (tid == 0) flag[0] = (sh_huge[0] || sh_zero[0] > 3600) ? 1 : 0;
}

// ---------------------------------------------------------------------------
// K1 fused prep: [0,256) gather, [256,1792) eatt, [1792,2560) t_seq,
//                [2560,3232) t_w, [3232,4000) t_bil(64k/blk)
#define PREP_GATHER 256
#define PREP_EATT   (PREP_GATHER + B_*E_*H_)     // +1536 -> 1792
#define PREP_TSEQ   (PREP_EATT + 768)            // -> 2560
#define PREP_TW     (PREP_TSEQ + 672)            // -> 3232
#define PREP_TBIL   (PREP_TW + 768)              // -> 4000

__global__ __launch_bounds__(256) void k_prep(
    const void* __restrict__ seq, const void* __restrict__ att,
    const int* __restrict__ epos, const int* __restrict__ spos,
    const int* __restrict__ vpos, const void* __restrict__ ntype,
    const void* __restrict__ Wh, const void* __restrict__ Wt_,
    const void* __restrict__ Wb,
    float* __restrict__ enth, float* __restrict__ e_att,
    unsigned short* __restrict__ seqT,
    unsigned short* __restrict__ WtH, unsigned short* __restrict__ WtT,
    unsigned short* __restrict__ WtB,
    void* __restrict__ outv, long long moff, long long soff, long long voff,
    const int* __restrict__ dflag)
{
    __shared__ __align__(16) unsigned char smem[12544];
    int blk = blockIdx.x, tid = threadIdx.x;
    int isf = *dflag;
    if (blk < PREP_GATHER) {
        if (blk < B_ * E_) {
            int b = blk / E_, e = blk % E_;
            int i0 = epos[(b * E_ + e) * K_ + 0] + 1;
            int i1 = epos[(b * E_ + e) * K_ + 1] + 1;
            size_t r0 = ((size_t)b * C_ + i0) * D_;
            size_t r1 = ((size_t)b * C_ + i1) * D_;
            size_t m0 = (size_t)moff + ((size_t)(b * E_ * K_) + 2 * e) * D_;
            size_t m1 = m0 + D_;
            float* eh = enth + (size_t)(b * E_ + e) * DNT_;
            for (int d = tid; d < D_; d += 256) {
                float a = ld_in(seq, r0 + d, isf);
                float c = ld_in(seq, r1 + d, isf);
                st_out(outv, m0 + d, a, isf);
                st_out(outv, m1 + d, c, isf);
                float mx = fmaxf(a, c);
                eh[d] = mx + logf(expf(a - mx) + expf(c - mx));
            }
            size_t nt0 = (size_t)(b * E_ + e) * NT_;
            for (int j = tid; j < NT_; j += 256) eh[D_ + j] = ld_in(ntype, nt0 + j, isf);
        } else if (blk < B_ * E_ + B_ * S_) {
            int t = blk - B_ * E_; int b = t / S_, s = t % S_;
            int i = spos[b * S_ + s] + 1;
            size_t r = ((size_t)b * C_ + i) * D_;
            size_t o = (size_t)soff + (size_t)(b * S_ + s) * D_;
            for (int d = tid; d < D_; d += 256) st_out(outv, o + d, ld_in(seq, r + d, isf), isf);
        } else {
            int t = blk - B_ * E_ - B_ * S_; int b = t / V_, v = t % V_;
            int i = vpos[b * V_ + v] + 1;
            size_t r = ((size_t)b * C_ + i) * D_;
            size_t o = (size_t)voff + (size_t)(b * V_ + v) * D_;
            for (int d = tid; d < D_; d += 256) st_out(outv, o + d, ld_in(seq, r + d, isf), isf);
        }
    } else if (blk < PREP_EATT) {
        int t = blk - PREP_GATHER;
        int b = t / (E_ * H_); int r = t % (E_ * H_); int e = r / H_; int h = r % H_;
        int i0 = epos[(b * E_ + e) * K_ + 0] + 1;
        int i1 = epos[(b * E_ + e) * K_ + 1] + 1;
        size_t a0 = (((size_t)b * H_ + h) * C_ + i0) * C_;
        size_t a1 = (((size_t)b * H_ + h) * C_ + i1) * C_;
        float* o = e_att + (((size_t)(b * E_ + e)) * H_ + h) * C_;
        for (int c = tid; c < C_; c += 256)
            o[c] = 0.5f * (ld_in(att, a0 + c, isf) + ld_in(att, a1 + c, isf));
    } else if (blk < PREP_TSEQ) {
        int t = blk - PREP_EATT;                 // b*192 + ct*12 + dt
        int b = t / 192; int r = t % 192; int ct = r / 12; int dt = r % 12;
        typedef unsigned short row65[65];
        row65* tile = (row65*)smem;
        for (int idx = tid; idx < 4096; idx += 256) {
            int cc = idx >> 6, dd = idx & 63;
            tile[cc][dd] = f2b(ld_in(seq, ((size_t)b * C_ + ct * 64 + cc) * D_ + dt * 64 + dd, isf));
        }
        __syncthreads();
        for (int idx = tid; idx < 4096; idx += 256) {
            int dd = idx >> 6, cc = idx & 63;
            seqT[((size_t)b * D_ + dt * 64 + dd) * C_ + ct * 64 + cc] = tile[cc][dd];
        }
    } else if (blk < PREP_TW) {
        int t = blk - PREP_TSEQ;                 // mat*336 + kt*12 + nt
        int mat = t / 336; int r = t % 336; int kt = r / 12; int nt = r % 12;
        const void* in = mat ? Wt_ : Wh;
        unsigned short* out = mat ? WtT : WtH;
        typedef unsigned short row65[65];
        row65* tile = (row65*)smem;
        for (int idx = tid; idx < 4096; idx += 256) {
            int kk = idx >> 6, nn = idx & 63;
            tile[kk][nn] = f2b(ld_in(in, ((size_t)kt * 64 + kk) * EMB_ + nt * 64 + nn, isf));
        }
        __syncthreads();
        for (int idx = tid; idx < 4096; idx += 256) {
            int nn = idx >> 6, kk = idx & 63;
            out[((size_t)nt * 64 + nn) * KHT_ + kt * 64 + kk] = tile[kk][nn];
        }
    } else {
        int t = blk - PREP_TW;                   // 64 k-cols per block
        int k0 = t << 6;
        unsigned short* raw = (unsigned short*)smem;   // [64*97]
        for (int idx = tid; idx < 64 * NL_; idx += 256)
            raw[idx] = f2b(ld_in(Wb, (size_t)k0 * NL_ + idx, isf));
        __syncthreads();
        int kk = tid & 63, nq = tid >> 6;              // 4 quarters x 32 n
        for (int i = 0; i < 32; i++) {
            int n = nq * 32 + i;
            unsigned short v = (n < NL_) ? raw[kk * NL_ + n] : (unsigned short)0;
            WtB[(size_t)n * KBIL_ + k0 + kk] = v;
        }
    }
}

// ---------------------------------------------------------------------------
// K2 fused mid: [0,2048) htatt, [2048,4096) xbuild, [4096,4352) zero logitsF
__global__ __launch_bounds__(256) void k_mid(
    const float* __restrict__ e_att, const float* __restrict__ enth,
    const int* __restrict__ hts,
    unsigned short* __restrict__ htb,
    unsigned short* __restrict__ Xh, unsigned short* __restrict__ Xt,
    float* __restrict__ logitsF)
{
    __shared__ float red[4];
    int blk = blockIdx.x, tid = threadIdx.x;
    if (blk < B_ * P_) {
        int b = blk >> 9;
        int he = hts[blk * 2 + 0], te = hts[blk * 2 + 1];
        const float* ph = e_att + (size_t)(b * E_ + he) * H_ * C_;
        const float* pt = e_att + (size_t)(b * E_ + te) * H_ * C_;
        float v[4]; float ls = 0.f;
        for (int ci = 0; ci < 4; ci++) {
            int c = tid + (ci << 8);
            float acc = 0.f;
#pragma unroll
            for (int h = 0; h < H_; h++) acc += ph[h * C_ + c] * pt[h * C_ + c];
            acc *= (1.0f / (float)H_);
            v[ci] = acc; ls += acc;
        }
        for (int off = 32; off > 0; off >>= 1) ls += __shfl_down(ls, off, 64);
        if ((tid & 63) == 0) red[tid >> 6] = ls;
        __syncthreads();
        float inv = 1.0f / (red[0] + red[1] + red[2] + red[3] + 1e-5f);
        for (int ci = 0; ci < 4; ci++)
            htb[((size_t)blk << 10) + tid + (ci << 8)] = f2b(v[ci] * inv);
    } else if (blk < 2 * B_ * P_) {
        int m = blk - B_ * P_; int b = m >> 9;
        int eh = hts[m * 2 + 0], et = hts[m * 2 + 1];
        const float* sh = enth + (size_t)(b * E_ + eh) * DNT_;
        const float* st = enth + (size_t)(b * E_ + et) * DNT_;
        for (int k = tid; k < DNT_; k += 256) {
            Xh[(size_t)m * KHT_ + k] = f2b(sh[k]);
            Xt[(size_t)m * KHT_ + k] = f2b(st[k]);
        }
    } else {
        int t = blk - 2 * B_ * P_;               // 256 blocks zero 1 MB
        ((float4*)logitsF)[(size_t)t * 256 + tid] = make_float4(0.f, 0.f, 0.f, 0.f);
    }
}

// ---------------------------------------------------------------------------
// bf16 MFMA GEMM, 64x64 tile, 4 waves 2x2, K-step 32, register prefetch.
// zmode 0 (rs): z = batch; epilogue writes bf16 into Xh/Xt cols DNT_+n.
// zmode 1 (ht): z = mat (0=head,1=tail); epilogue bf16 tanh(acc+bias) -> oY.
__global__ __launch_bounds__(256) void k_gemm(
    const unsigned short* __restrict__ A0, const unsigned short* __restrict__ A1,
    const unsigned short* __restrict__ B0, const unsigned short* __restrict__ B1,
    long long lda, long long ldb, long long sAz, long long sBz,
    int nsteps, int zmode,
    const void* __restrict__ bias0, const void* __restrict__ bias1,
    unsigned short* __restrict__ oY0, unsigned short* __restrict__ oY1,
    unsigned short* __restrict__ oX1, unsigned short* __restrict__ oX2,
    const int* __restrict__ dflag)
{
    int n0 = blockIdx.x * 64, m0 = blockIdx.y * 64, z = blockIdx.z;
    const unsigned short* Ab; const unsigned short* Bb;
    unsigned short* oY = nullptr; const void* bias = nullptr;
    if (zmode == 0) {
        Ab = A0 + (size_t)z * sAz; Bb = B0 + (size_t)z * sBz;
    } else {
        Ab = z ? A1 : A0; Bb = z ? B1 : B0;
        oY = z ? oY1 : oY0; bias = z ? bias1 : bias0;
    }
    __shared__ __align__(16) unsigned short a_lds[64][40];
    __shared__ __align__(16) unsigned short b_lds[64][40];
    int tid = threadIdx.x, lane = tid & 63, w = tid >> 6;
    int wm = (w >> 1) * 32, wn = (w & 1) * 32, q = lane >> 4, l15 = lane & 15;
    f32x4 acc00 = {0.f,0.f,0.f,0.f}, acc01 = acc00, acc10 = acc00, acc11 = acc00;
    int srow = tid >> 2, sch = (tid & 3) * 8;
    const unsigned short* pa = Ab + (size_t)(m0 + srow) * lda + sch;
    const unsigned short* pb = Bb + (size_t)(n0 + srow) * ldb + sch;
    int4 ra = *(const int4*)pa;
    int4 rb = *(const int4*)pb;
    for (int ks = 0; ks < nsteps; ks++) {
        __syncthreads();
        *(int4*)&a_lds[srow][sch] = ra;
        *(int4*)&b_lds[srow][sch] = rb;
        __syncthreads();
        if (ks + 1 < nsteps) {
            ra = *(const int4*)(pa + (size_t)(ks + 1) * 32);
            rb = *(const int4*)(pb + (size_t)(ks + 1) * 32);
        }
        bf16x8 a0 = *(const bf16x8*)&a_lds[wm + l15][q * 8];
        bf16x8 a1 = *(const bf16x8*)&a_lds[wm + 16 + l15][q * 8];
        bf16x8 b0 = *(const bf16x8*)&b_lds[wn + l15][q * 8];
        bf16x8 b1 = *(const bf16x8*)&b_lds[wn + 16 + l15][q * 8];
        acc00 = __builtin_amdgcn_mfma_f32_16x16x32_bf16(a0, b0, acc00, 0, 0, 0);
        acc01 = __builtin_amdgcn_mfma_f32_16x16x32_bf16(a0, b1, acc01, 0, 0, 0);
        acc10 = __builtin_amdgcn_mfma_f32_16x16x32_bf16(a1, b0, acc10, 0, 0, 0);
        acc11 = __builtin_amdgcn_mfma_f32_16x16x32_bf16(a1, b1, acc11, 0, 0, 0);
    }
    f32x4 accs[2][2] = {{acc00, acc01}, {acc10, acc11}};
    int isf = (zmode == 1) ? *dflag : 0;
#pragma unroll
    for (int mt = 0; mt < 2; mt++)
#pragma unroll
        for (int nt = 0; nt < 2; nt++) {
            int gmb = m0 + wm + mt * 16 + q * 4;
            int gn  = n0 + wn + nt * 16 + l15;
            if (zmode == 0) {
#pragma unroll
                for (int r = 0; r < 4; r++) {
                    unsigned short v = f2b(accs[mt][nt][r]);
                    size_t o = (size_t)(z * P_ + gmb + r) * KHT_ + DNT_ + gn;
                    oX1[o] = v; oX2[o] = v;
                }
            } else {
                float bv = ld_in(bias, gn, isf);
#pragma unroll
                for (int r = 0; r < 4; r++)
                    oY[(size_t)(gmb + r) * EMB_ + gn] = f2b(tanhf(accs[mt][nt][r] + bv));
            }
        }
}

// ---------------------------------------------------------------------------
// Grouped bilinear via MFMA, K split over groups (grid.y = g), atomic f32 acc.
// hs/ts arrive pre-tanh'd in bf16. Depth-2 B-fragment prefetch.
__global__ __launch_bounds__(256) void k_bil(
    const unsigned short* __restrict__ hsB, const unsigned short* __restrict__ tsB,
    const unsigned short* __restrict__ WtB, float* __restrict__ logitsF)
{
    int m0 = blockIdx.x * 32;
    int g  = blockIdx.y;
    int tid = threadIdx.x, lane = tid & 63, w = tid >> 6;
    int q = lane >> 4, l15 = lane & 15;
    __shared__ __align__(16) unsigned short hsl[32][80];   // 160 B rows (16B-aligned)
    __shared__ __align__(16) unsigned short tsl[32][80];
    for (int idx = tid; idx < 512; idx += 256) {
        int m = idx >> 4, j4 = (idx & 15) * 4;
        *(ushort4*)&hsl[m][j4] = *(const ushort4*)&hsB[(size_t)(m0 + m) * EMB_ + g * 64 + j4];
        *(ushort4*)&tsl[m][j4] = *(const ushort4*)&tsB[(size_t)(m0 + m) * EMB_ + g * 64 + j4];
    }
    __syncthreads();

    const unsigned short* pB0 = WtB + (size_t)(w * 16 + l15) * KBIL_ + g * 4096 + q * 8;
    const unsigned short* pB1 = pB0 + (size_t)64 * KBIL_;
    bf16x8 rb0[2], rb1[2];
    rb0[0] = *(const bf16x8*)(pB0);      rb1[0] = *(const bf16x8*)(pB1);
    rb0[1] = *(const bf16x8*)(pB0 + 32); rb1[1] = *(const bf16x8*)(pB1 + 32);
    f32x4 acc00 = {0.f,0.f,0.f,0.f}, acc01 = acc00, acc10 = acc00, acc11 = acc00;

#pragma unroll 2
    for (int kk = 0; kk < 128; kk++) {
        int sl = kk & 1;
        bf16x8 bw0 = rb0[sl], bw1 = rb1[sl];
        if (kk + 2 < 128) {
            rb0[sl] = *(const bf16x8*)(pB0 + (size_t)(kk + 2) * 32);
            rb1[sl] = *(const bf16x8*)(pB1 + (size_t)(kk + 2) * 32);
        }
        int i = kk >> 1, h = kk & 1;
        float ha0 = b2f(hsl[l15][i]);
        float ha1 = b2f(hsl[16 + l15][i]);
        bf16x8 t0 = *(const bf16x8*)&tsl[l15][h * 32 + q * 8];
        bf16x8 t1 = *(const bf16x8*)&tsl[16 + l15][h * 32 + q * 8];
        bf16x8 af0, af1;
#pragma unroll
        for (int j = 0; j < 8; j++) {
            af0[j] = (__bf16)(ha0 * (float)t0[j]);
            af1[j] = (__bf16)(ha1 * (float)t1[j]);
        }
        acc00 = __builtin_amdgcn_mfma_f32_16x16x32_bf16(af0, bw0, acc00, 0, 0, 0);
        acc01 = __builtin_amdgcn_mfma_f32_16x16x32_bf16(af0, bw1, acc01, 0, 0, 0);
        acc10 = __builtin_amdgcn_mfma_f32_16x16x32_bf16(af1, bw0, acc10, 0, 0, 0);
        acc11 = __builtin_amdgcn_mfma_f32_16x16x32_bf16(af1, bw1, acc11, 0, 0, 0);
    }
#pragma unroll
    for (int r = 0; r < 4; r++) {
        atomicAdd(&logitsF[(size_t)(m0 + q * 4 + r) * NPAD_ + w * 16 + l15],           acc00[r]);
        atomicAdd(&logitsF[(size_t)(m0 + q * 4 + r) * NPAD_ + w * 16 + 64 + l15],      acc01[r]);
        atomicAdd(&logitsF[(size_t)(m0 + 16 + q * 4 + r) * NPAD_ + w * 16 + l15],      acc10[r]);
        atomicAdd(&logitsF[(size_t)(m0 + 16 + q * 4 + r) * NPAD_ + w * 16 + 64 + l15], acc11[r]);
    }
}

// ---------------------------------------------------------------------------
// final: logits out with bias, n<97
__global__ __launch_bounds__(256) void k_fin(
    const float* __restrict__ logitsF, const void* __restrict__ b_bil,
    void* __restrict__ outv, const int* __restrict__ dflag)
{
    int isf = *dflag;
    int idx = blockIdx.x * 256 + threadIdx.x;
    if (idx >= B_ * P_ * NL_) return;
    int m = idx / NL_, n = idx % NL_;
    st_out(outv, idx, logitsF[(size_t)m * NPAD_ + n] + ld_in(b_bil, n, isf), isf);
}

// ---------------------------------------------------------------------------
extern "C" void kernel_launch(void* const* d_in, const int* in_sizes, int n_in,
                              void* d_out, int out_size, void* d_ws, size_t ws_size,
                              hipStream_t stream)
{
    const void* seq    = d_in[0];
    const void* att    = d_in[1];
    const int*  epos   = (const int*)d_in[2];
    const int*  spos   = (const int*)d_in[3];
    const int*  vpos   = (const int*)d_in[4];
    const int*  hts    = (const int*)d_in[5];
    const void* ntype  = d_in[6];
    const void* W_head = d_in[7];
    const void* b_head = d_in[8];
    const void* W_tail = d_in[9];
    const void* b_tail = d_in[10];
    const void* W_bil  = d_in[11];
    const void* b_bil  = d_in[12];

    // output element offsets (dtype-agnostic)
    long long mention_off = (long long)B_ * P_ * NL_;
    long long sent_off    = mention_off + (long long)B_ * E_ * K_ * D_;
    long long virt_off    = sent_off + (long long)B_ * S_ * D_;

    // workspace carve (~60 MB)
    char* p = (char*)d_ws;
    auto alloc = [&](size_t bytes) { void* r = (void*)p; p += (bytes + 255) & ~(size_t)255; return r; };
    int*            dflag   = (int*)alloc(256);
    float*          e_att   = (float*)alloc((size_t)B_ * E_ * H_ * C_ * 4);
    unsigned short* htb     = (unsigned short*)alloc((size_t)B_ * P_ * C_ * 2);
    unsigned short* seqT    = (unsigned short*)alloc((size_t)B_ * D_ * C_ * 2);
    unsigned short* WtH     = (unsigned short*)alloc((size_t)EMB_ * KHT_ * 2);
    unsigned short* WtT     = (unsigned short*)alloc((size_t)EMB_ * KHT_ * 2);
    unsigned short* WtB     = (unsigned short*)alloc((size_t)NPAD_ * KBIL_ * 2);
    unsigned short* Xh      = (unsigned short*)alloc((size_t)B_ * P_ * KHT_ * 2);
    unsigned short* Xt      = (unsigned short*)alloc((size_t)B_ * P_ * KHT_ * 2);
    unsigned short* hsB     = (unsigned short*)alloc((size_t)B_ * P_ * EMB_ * 2);
    unsigned short* tsB     = (unsigned short*)alloc((size_t)B_ * P_ * EMB_ * 2);
    float*          logitsF = (float*)alloc((size_t)B_ * P_ * NPAD_ * 4);
    float*          enth    = (float*)alloc((size_t)B_ * E_ * DNT_ * 4);

    dim3 blk(256);
    k_probe<<<1, blk, 0, stream>>>((const unsigned short*)seq, dflag);
    k_prep<<<PREP_TBIL, blk, 0, stream>>>(
        seq, att, epos, spos, vpos, ntype, W_head, W_tail, W_bil,
        enth, e_att, seqT, WtH, WtT, WtB,
        d_out, mention_off, sent_off, virt_off, dflag);
    k_mid<<<2 * B_ * P_ + 256, blk, 0, stream>>>(e_att, enth, hts, htb, Xh, Xt, logitsF);
    // rs GEMM: per batch [512 x 1024] @ [1024 x 768] -> X cols 1024..1791 (bf16)
    k_gemm<<<dim3(EMB_ / 64, P_ / 64, B_), blk, 0, stream>>>(
        htb, nullptr, seqT, nullptr, C_, C_,
        (long long)P_ * C_, (long long)D_ * C_, C_ / 32, 0,
        nullptr, nullptr, nullptr, nullptr, Xh, Xt, dflag);
    // fused head+tail: [2048 x 1792] @ [1792 x 768], tanh+bias -> bf16 hsB/tsB
    k_gemm<<<dim3(EMB_ / 64, (B_ * P_) / 64, 2), blk, 0, stream>>>(
        Xh, Xt, WtH, WtT, KHT_, KHT_, 0, 0, KHT_ / 32, 1,
        b_head, b_tail, hsB, tsB, nullptr, nullptr, dflag);
    k_bil<<<dim3((B_ * P_) / 32, 12, 1), blk, 0, stream>>>(hsB, tsB, WtB, logitsF);
    k_fin<<<(B_ * P_ * NL_ + 255) / 256, blk, 0, stream>>>(logitsF, b_bil, d_out, dflag);
}